// Round 4
// baseline (5088.181 us; speedup 1.0000x reference)
//
#include <hip/hip_runtime.h>
#include <hip/hip_bf16.h>
#include <math.h>

#define NNODE 200000
#define EMBD  128
#define TT    32
#define EE    100000
#define AA    4096
#define BB    2048
#define USERN 150000
#define COMPN 49998
#define NPAD  50048   // 391*128
#define NT2   391     // lse n-tiles of 128

typedef __attribute__((ext_vector_type(8))) short short8;
typedef __attribute__((ext_vector_type(4))) float f32x4;

__device__ __forceinline__ short f2bf(float f) {
    unsigned u = __float_as_uint(f);
    unsigned r = (u + 0x7fffu + ((u >> 16) & 1u)) >> 16;   // RNE
    return (short)r;
}
__device__ __forceinline__ float sig(float x) { return 1.f / (1.f + __expf(-x)); }

// ---------------- init ----------------
__global__ void init_kernel(const float4* __restrict__ ent, const float4* __restrict__ c0,
                            float4* __restrict__ node, float4* __restrict__ cxp,
                            float4* __restrict__ msg, float* __restrict__ cnt,
                            float* __restrict__ out) {
    const long NV = (long)NNODE * EMBD / 4;
    long i0 = (long)blockIdx.x * blockDim.x + threadIdx.x;
    long stride = (long)gridDim.x * blockDim.x;
    float4 z = make_float4(0.f, 0.f, 0.f, 0.f);
    for (long i = i0; i < NV; i += stride) { node[i] = ent[i]; cxp[i] = c0[i]; msg[i] = z; }
    for (long i = i0; i < NNODE; i += stride) cnt[i] = 0.f;
    if (i0 == 0) out[0] = 0.f;
}

// ---------------- once: convert W (gate-concat), biases, comp embeddings to bf16 ----------------
__global__ void convert_kernel(const float* __restrict__ Wih, const float* __restrict__ Whh,
                               const float* __restrict__ bih, const float* __restrict__ bhh,
                               const float* __restrict__ ent,
                               short* __restrict__ w16, float* __restrict__ bsum,
                               short* __restrict__ c16) {
    long i0 = (long)blockIdx.x * blockDim.x + threadIdx.x;
    long stride = (long)gridDim.x * blockDim.x;
    for (long i = i0; i < 512 * 256; i += stride) {
        int n = i >> 8, k = i & 255;
        float v = (k < 128) ? Wih[(size_t)n * 128 + k] : Whh[(size_t)n * 128 + (k - 128)];
        w16[i] = f2bf(v);
    }
    for (long i = i0; i < 512; i += stride) bsum[i] = bih[i] + bhh[i];
    for (long i = i0; i < (long)NPAD * 128; i += stride) {
        long r = i >> 7;
        float v = (r < COMPN) ? ent[(size_t)(USERN + r) * 128 + (i & 127)] : 0.f;
        c16[i] = f2bf(v);
    }
}

// ---------------- L1: edges scatter || snapshot(t-1) || stamp act_t ----------------
__global__ __launch_bounds__(512) void l1_kernel(const int* __restrict__ src, const int* __restrict__ dst,
                                                 const float* __restrict__ node, float* __restrict__ msg,
                                                 float* __restrict__ cnt,
                                                 const int* __restrict__ su, const int* __restrict__ st,
                                                 float* __restrict__ u_emb, short* __restrict__ u16,
                                                 const int* __restrict__ act_t, int* __restrict__ stamp,
                                                 int t) {
    int blk = blockIdx.x;
    int tid = threadIdx.x;
    if (blk < EE / 4) {                       // edges
        int e = blk * 4 + tid / 128;
        int d = tid % 128;
        int s = src[e];
        int v = dst[e];
        atomicAdd(&msg[(size_t)v * 128 + d], node[(size_t)s * 128 + d]);
        if (d == 0) atomicAdd(&cnt[v], 1.0f);
    } else if (blk < EE / 4 + BB / 4) {       // snapshot rows with seed_time == t-1
        if (t == 0) return;
        int b = (blk - EE / 4) * 4 + tid / 128;
        int d = tid % 128;
        if (st[b] == t - 1) {
            float v = node[(size_t)su[b] * 128 + d];
            u_emb[(size_t)b * 128 + d] = v;
            u16[(size_t)b * 128 + d] = f2bf(v);
        }
    } else {                                  // stamp act rows for this step
        int idx = (blk - (EE / 4 + BB / 4)) * 512 + tid;
        if (idx < AA) stamp[act_t[idx]] = t + 1;
    }
}

// ---------------- L2: build xh16 = [x | prev_h] in bf16 ----------------
__global__ __launch_bounds__(512) void build_xh(const int* __restrict__ act, const float* __restrict__ node,
                                                const float* __restrict__ msg, const float* __restrict__ cnt,
                                                short* __restrict__ xh16) {
    int a = blockIdx.x * 4 + threadIdx.x / 128;
    int d = threadIdx.x % 128;
    int v = act[a];
    float ph = node[(size_t)v * 128 + d];
    float c = cnt[v];
    float ag = (c > 0.f) ? msg[(size_t)v * 128 + d] / c : 0.f;
    xh16[(size_t)a * 256 + d] = f2bf(ph + ag);
    xh16[(size_t)a * 256 + 128 + d] = f2bf(ph);
}

// ---------------- L3: fused [MFMA gates + LSTM epilogue] (blk<128) || apply (rest) ----------------
__global__ __launch_bounds__(512) void l3_kernel(const short* __restrict__ xh16,
                                                 const short* __restrict__ w16,
                                                 const float* __restrict__ bsum,
                                                 const int* __restrict__ act_t,
                                                 const int* __restrict__ stamp,
                                                 float* __restrict__ node, float* __restrict__ cxp,
                                                 float* __restrict__ msg, float* __restrict__ cnt,
                                                 int t) {
    int blk = blockIdx.x;
    int tid = threadIdx.x;
    if (blk < 128) {
        // gates = XH(4096x256) @ Wcat^T, gate-interleaved col mapping, fused LSTM epilogue
        int m0 = blk * 32;
        int w = tid >> 6;           // wave 0..7
        int wm = w >> 2;            // m-subtile 0..1
        int cg = w & 3;             // d-column group (32 wide)
        int lane = tid & 63;
        int la = lane & 15, lb = lane >> 4;
        int m_a = m0 + wm * 16 + la;
        f32x4 acc[8] = {};
#pragma unroll
        for (int kc = 0; kc < 8; ++kc) {
            short8 af = *(const short8*)&xh16[(size_t)m_a * 256 + kc * 32 + lb * 8];
#pragma unroll
            for (int s = 0; s < 8; ++s) {
                int n = (s & 3) * 128 + cg * 32 + (s >> 2) * 16 + la;
                short8 bf = *(const short8*)&w16[(size_t)n * 256 + kc * 32 + lb * 8];
                acc[s] = __builtin_amdgcn_mfma_f32_16x16x32_bf16(af, bf, acc[s], 0, 0, 0);
            }
        }
#pragma unroll
        for (int half = 0; half < 2; ++half) {
            int d = cg * 32 + half * 16 + la;
            float b_i = bsum[d], b_f = bsum[128 + d], b_g = bsum[256 + d], b_o = bsum[384 + d];
#pragma unroll
            for (int r = 0; r < 4; ++r) {
                int row = m0 + wm * 16 + lb * 4 + r;
                int v = act_t[row];
                float gi = acc[half * 4 + 0][r] + b_i;
                float gf = acc[half * 4 + 1][r] + b_f;
                float gg = acc[half * 4 + 2][r] + b_g;
                float go = acc[half * 4 + 3][r] + b_o;
                float pc = cxp[(size_t)v * 128 + d];
                float c_ = sig(gf) * pc + sig(gi) * tanhf(gg);
                float h_ = sig(go) * tanhf(c_);
                node[(size_t)v * 128 + d] = h_;
                cxp[(size_t)v * 128 + d] = c_;
                msg[(size_t)v * 128 + d] = 0.f;   // act rows skipped by apply: zero here
            }
        }
        if (la == 0 && cg == 0) {
#pragma unroll
            for (int r = 0; r < 4; ++r) cnt[act_t[m0 + wm * 16 + lb * 4 + r]] = 0.f;
        }
    } else {
        // apply agg to non-act nodes, re-zero msg/cnt
        int v = (blk - 128) * 4 + tid / 128;
        int d = tid % 128;
        if (v >= NNODE) return;
        if (stamp[v] == t + 1) return;          // act row: handled by fused gemm
        float c = cnt[v];
        if (c > 0.f) {
            node[(size_t)v * 128 + d] += msg[(size_t)v * 128 + d] / c;
            msg[(size_t)v * 128 + d] = 0.f;
            if (d == 0) cnt[v] = 0.f;
        }
    }
}

// ---------------- post-loop: snapshot t=31 ----------------
__global__ __launch_bounds__(512) void snap31(const float* __restrict__ node, const int* __restrict__ su,
                                              const int* __restrict__ st, float* __restrict__ u_emb,
                                              short* __restrict__ u16) {
    int b = blockIdx.x * 4 + threadIdx.x / 128;
    int d = threadIdx.x % 128;
    if (st[b] == TT - 1) {
        float v = node[(size_t)su[b] * 128 + d];
        u_emb[(size_t)b * 128 + d] = v;
        u16[(size_t)b * 128 + d] = f2bf(v);
    }
}

// ---------------- final: bf16 MFMA lse partials (128x128 tile / block, no LDS) ----------------
__global__ __launch_bounds__(512) void lse_mfma(const short* __restrict__ u16,
                                                const short* __restrict__ c16,
                                                float* __restrict__ pm, float* __restrict__ ps) {
    int n0 = blockIdx.x * 128;
    int m0 = blockIdx.y * 128;
    int tid = threadIdx.x;
    int w = tid >> 6;           // 8 waves: 16-row strip each
    int lane = tid & 63;
    int la = lane & 15, lb = lane >> 4;
    int m_a = m0 + w * 16 + la;
    f32x4 acc[8] = {};
#pragma unroll
    for (int kc = 0; kc < 4; ++kc) {
        short8 af = *(const short8*)&u16[(size_t)m_a * 128 + kc * 32 + lb * 8];
#pragma unroll
        for (int s = 0; s < 8; ++s) {
            int n = n0 + s * 16 + la;
            short8 bf = *(const short8*)&c16[(size_t)n * 128 + kc * 32 + lb * 8];
            acc[s] = __builtin_amdgcn_mfma_f32_16x16x32_bf16(af, bf, acc[s], 0, 0, 0);
        }
    }
#pragma unroll
    for (int r = 0; r < 4; ++r) {
        int row = m0 + w * 16 + lb * 4 + r;
        float mx = -3.4e38f;
#pragma unroll
        for (int s = 0; s < 8; ++s)
            if (n0 + s * 16 + la < COMPN) mx = fmaxf(mx, acc[s][r]);
#pragma unroll
        for (int off = 1; off < 16; off <<= 1) mx = fmaxf(mx, __shfl_xor(mx, off));
        float sm = 0.f;
#pragma unroll
        for (int s = 0; s < 8; ++s)
            if (n0 + s * 16 + la < COMPN) sm += __expf(acc[s][r] - mx);
#pragma unroll
        for (int off = 1; off < 16; off <<= 1) sm += __shfl_xor(sm, off);
        if (la == 0) {
            pm[(size_t)blockIdx.x * BB + row] = mx;
            ps[(size_t)blockIdx.x * BB + row] = sm;
        }
    }
}

// ---------------- final: merge per-tile partials ----------------
__global__ void lse_merge(const float* __restrict__ pm, const float* __restrict__ ps,
                          float* __restrict__ lse_row) {
    int row = blockIdx.x * 256 + threadIdx.x;
    float m = -3.4e38f, s = 0.f;
    for (int c = 0; c < NT2; ++c) {
        float mi = pm[(size_t)c * BB + row];
        float si = ps[(size_t)c * BB + row];
        if (mi > m) { s = s * __expf(m - mi) + si; m = mi; }
        else        { s += si * __expf(mi - m); }
    }
    lse_row[row] = m + logf(s);
}

// ---------------- final: loss ----------------
__global__ void final_k(const float* __restrict__ u_emb, const float* __restrict__ ent,
                        const int* __restrict__ crel, const float* __restrict__ lse_row,
                        float* __restrict__ out) {
    int b = blockIdx.x * 256 + threadIdx.x;
    if (b >= BB) return;
    float lse = lse_row[b];
    const float* u = &u_emb[(size_t)b * 128];
    const float* c = &ent[(size_t)(USERN + crel[b]) * 128];
    float pos = 0.f;
#pragma unroll
    for (int k = 0; k < 128; k += 4) {
        float4 uv = *(const float4*)&u[k];
        float4 cv = *(const float4*)&c[k];
        pos += uv.x * cv.x + uv.y * cv.y + uv.z * cv.z + uv.w * cv.w;
    }
    atomicAdd(out, lse - pos);
}

extern "C" void kernel_launch(void* const* d_in, const int* in_sizes, int n_in,
                              void* d_out, int out_size, void* d_ws, size_t ws_size,
                              hipStream_t stream) {
    const float* ent  = (const float*)d_in[0];
    const float* c0   = (const float*)d_in[1];
    const float* Wih  = (const float*)d_in[2];
    const float* Whh  = (const float*)d_in[3];
    const float* bih  = (const float*)d_in[4];
    const float* bhh  = (const float*)d_in[5];
    const int* esrc   = (const int*)d_in[6];
    const int* edst   = (const int*)d_in[7];
    const int* act    = (const int*)d_in[8];
    const int* susr   = (const int*)d_in[9];
    const int* stime  = (const int*)d_in[10];
    const int* crel   = (const int*)d_in[11];
    float* out = (float*)d_out;

    float* ws = (float*)d_ws;
    size_t o = 0;
    float* node  = ws + o; o += (size_t)NNODE * EMBD;
    float* cxp   = ws + o; o += (size_t)NNODE * EMBD;
    float* msg   = ws + o; o += (size_t)NNODE * EMBD;
    float* u_emb = ws + o; o += (size_t)BB * 128;
    float* lse_row = ws + o; o += (size_t)BB;
    float* cnt   = ws + o; o += (size_t)NNODE;
    short* xh16  = (short*)(ws + o); o += (size_t)AA * 256 / 2;
    short* w16   = (short*)(ws + o); o += (size_t)512 * 256 / 2;
    float* bsum  = ws + o; o += 512;
    short* c16   = (short*)(ws + o); o += (size_t)NPAD * 128 / 2;
    short* u16   = (short*)(ws + o); o += (size_t)BB * 128 / 2;
    int*   stamp = (int*)(ws + o); o += NNODE;
    // lse partials reuse msg (idle post-loop; re-zeroed by init each launch)
    float* pm = msg;
    float* ps = msg + (size_t)NT2 * BB;

    init_kernel<<<2048, 256, 0, stream>>>((const float4*)ent, (const float4*)c0,
                                          (float4*)node, (float4*)cxp, (float4*)msg, cnt, out);
    convert_kernel<<<2048, 256, 0, stream>>>(Wih, Whh, bih, bhh, ent, w16, bsum, c16);

    const int L1_GRID = EE / 4 + BB / 4 + (AA + 511) / 512;   // 25000 + 512 + 8
    const int L3_GRID = 128 + NNODE / 4;                      // 128 + 50000
    for (int t = 0; t < TT; ++t) {
        const int* src_t = esrc + (size_t)t * EE;
        const int* dst_t = edst + (size_t)t * EE;
        const int* act_t = act + (size_t)t * AA;
        l1_kernel<<<L1_GRID, 512, 0, stream>>>(src_t, dst_t, node, msg, cnt,
                                               susr, stime, u_emb, u16, act_t, stamp, t);
        build_xh<<<AA / 4, 512, 0, stream>>>(act_t, node, msg, cnt, xh16);
        l3_kernel<<<L3_GRID, 512, 0, stream>>>(xh16, w16, bsum, act_t, stamp,
                                               node, cxp, msg, cnt, t);
    }

    snap31<<<BB / 4, 512, 0, stream>>>(node, susr, stime, u_emb, u16);
    lse_mfma<<<dim3(NT2, BB / 128), 512, 0, stream>>>(u16, c16, pm, ps);
    lse_merge<<<BB / 256, 256, 0, stream>>>(pm, ps, lse_row);
    final_k<<<BB / 256, 256, 0, stream>>>(u_emb, ent, crel, lse_row, out);
}

// Round 5
// 4202.230 us; speedup vs baseline: 1.2108x; 1.2108x over previous
//
#include <hip/hip_runtime.h>
#include <hip/hip_bf16.h>
#include <math.h>

#define NNODE 200000
#define EMBD  128
#define TT    32
#define EE    100000
#define AA    4096
#define BB    2048
#define USERN 150000
#define COMPN 49998
#define NPAD  50048   // 391*128
#define NT2   391     // lse n-tiles of 128

typedef __attribute__((ext_vector_type(8))) short short8;
typedef __attribute__((ext_vector_type(4))) float f32x4;

__device__ __forceinline__ short f2bf(float f) {
    unsigned u = __float_as_uint(f);
    unsigned r = (u + 0x7fffu + ((u >> 16) & 1u)) >> 16;   // RNE
    return (short)r;
}
__device__ __forceinline__ float sig(float x) { return 1.f / (1.f + __expf(-x)); }

// ---------------- init ----------------
__global__ void init_kernel(const float4* __restrict__ ent, const float4* __restrict__ c0,
                            float4* __restrict__ node, float4* __restrict__ cxp,
                            float4* __restrict__ msg, float* __restrict__ cnt,
                            float* __restrict__ out) {
    const long NV = (long)NNODE * EMBD / 4;
    long i0 = (long)blockIdx.x * blockDim.x + threadIdx.x;
    long stride = (long)gridDim.x * blockDim.x;
    float4 z = make_float4(0.f, 0.f, 0.f, 0.f);
    for (long i = i0; i < NV; i += stride) { node[i] = ent[i]; cxp[i] = c0[i]; msg[i] = z; }
    for (long i = i0; i < NNODE; i += stride) cnt[i] = 0.f;
    if (i0 == 0) out[0] = 0.f;
}

// ---------------- once: convert W (gate-concat), biases, comp embeddings to bf16 ----------------
__global__ void convert_kernel(const float* __restrict__ Wih, const float* __restrict__ Whh,
                               const float* __restrict__ bih, const float* __restrict__ bhh,
                               const float* __restrict__ ent,
                               short* __restrict__ w16, float* __restrict__ bsum,
                               short* __restrict__ c16) {
    long i0 = (long)blockIdx.x * blockDim.x + threadIdx.x;
    long stride = (long)gridDim.x * blockDim.x;
    for (long i = i0; i < 512 * 256; i += stride) {
        int n = i >> 8, k = i & 255;
        float v = (k < 128) ? Wih[(size_t)n * 128 + k] : Whh[(size_t)n * 128 + (k - 128)];
        w16[i] = f2bf(v);
    }
    for (long i = i0; i < 512; i += stride) bsum[i] = bih[i] + bhh[i];
    for (long i = i0; i < (long)NPAD * 128; i += stride) {
        long r = i >> 7;
        float v = (r < COMPN) ? ent[(size_t)(USERN + r) * 128 + (i & 127)] : 0.f;
        c16[i] = f2bf(v);
    }
}

// ---------------- per-step: edge scatter ----------------
__global__ void edge_kernel(const int* __restrict__ src, const int* __restrict__ dst,
                            const float* __restrict__ node, float* __restrict__ msg,
                            float* __restrict__ cnt) {
    int e = blockIdx.x * 2 + threadIdx.x / 128;
    int d = threadIdx.x % 128;
    int s = src[e];
    int v = dst[e];
    atomicAdd(&msg[(size_t)v * 128 + d], node[(size_t)s * 128 + d]);
    if (d == 0) atomicAdd(&cnt[v], 1.0f);
}

// ---------------- per-step: build xh16 = [x | prev_h] bf16 (pre-update gather) ----------------
__global__ __launch_bounds__(512) void build_xh(const int* __restrict__ act, const float* __restrict__ node,
                                                const float* __restrict__ msg, const float* __restrict__ cnt,
                                                short* __restrict__ xh16) {
    int a = blockIdx.x * 4 + threadIdx.x / 128;
    int d = threadIdx.x % 128;
    int v = act[a];
    float ph = node[(size_t)v * 128 + d];
    float c = cnt[v];
    float ag = (c > 0.f) ? msg[(size_t)v * 128 + d] / c : 0.f;
    xh16[(size_t)a * 256 + d] = f2bf(ph + ag);
    xh16[(size_t)a * 256 + 128 + d] = f2bf(ph);
}

// ---------------- per-step: apply agg to node, re-zero msg/cnt (all touched rows) ----------------
__global__ void apply_kernel(float* __restrict__ node, float* __restrict__ msg,
                             float* __restrict__ cnt) {
    int v = blockIdx.x * 2 + threadIdx.x / 128;
    int d = threadIdx.x % 128;
    float c = cnt[v];
    if (c > 0.f) {
        node[(size_t)v * 128 + d] += msg[(size_t)v * 128 + d] / c;
        msg[(size_t)v * 128 + d] = 0.f;
        if (d == 0) cnt[v] = 0.f;
    }
}

// ---------------- per-step: MFMA gates + fused LSTM epilogue (overwrites act rows) ----------------
__global__ __launch_bounds__(512) void gates_mfma(const short* __restrict__ xh16,
                                                  const short* __restrict__ w16,
                                                  const float* __restrict__ bsum,
                                                  const int* __restrict__ act_t,
                                                  float* __restrict__ node, float* __restrict__ cxp) {
    int m0 = blockIdx.x * 32;
    int tid = threadIdx.x;
    int w = tid >> 6;           // wave 0..7
    int wm = w >> 2;            // m-subtile 0..1
    int cg = w & 3;             // d-column group (32 wide)
    int lane = tid & 63;
    int la = lane & 15, lb = lane >> 4;
    int m_a = m0 + wm * 16 + la;
    f32x4 acc[8] = {};
#pragma unroll
    for (int kc = 0; kc < 8; ++kc) {
        short8 af = *(const short8*)&xh16[(size_t)m_a * 256 + kc * 32 + lb * 8];
#pragma unroll
        for (int s = 0; s < 8; ++s) {
            int n = (s & 3) * 128 + cg * 32 + (s >> 2) * 16 + la;
            short8 bf = *(const short8*)&w16[(size_t)n * 256 + kc * 32 + lb * 8];
            acc[s] = __builtin_amdgcn_mfma_f32_16x16x32_bf16(af, bf, acc[s], 0, 0, 0);
        }
    }
#pragma unroll
    for (int half = 0; half < 2; ++half) {
        int d = cg * 32 + half * 16 + la;
        float b_i = bsum[d], b_f = bsum[128 + d], b_g = bsum[256 + d], b_o = bsum[384 + d];
#pragma unroll
        for (int r = 0; r < 4; ++r) {
            int row = m0 + wm * 16 + lb * 4 + r;
            int v = act_t[row];
            float gi = acc[half * 4 + 0][r] + b_i;
            float gf = acc[half * 4 + 1][r] + b_f;
            float gg = acc[half * 4 + 2][r] + b_g;
            float go = acc[half * 4 + 3][r] + b_o;
            float pc = cxp[(size_t)v * 128 + d];
            float c_ = sig(gf) * pc + sig(gi) * tanhf(gg);
            float h_ = sig(go) * tanhf(c_);
            node[(size_t)v * 128 + d] = h_;
            cxp[(size_t)v * 128 + d] = c_;
        }
    }
}

// ---------------- per-step: snapshot rows whose seed_time == t ----------------
__global__ void snapshot_k(const float* __restrict__ node, const int* __restrict__ su,
                           const int* __restrict__ st, float* __restrict__ u_emb,
                           short* __restrict__ u16, int t) {
    int b = blockIdx.x * 2 + threadIdx.x / 128;
    int d = threadIdx.x % 128;
    if (st[b] == t) {
        float v = node[(size_t)su[b] * 128 + d];
        u_emb[(size_t)b * 128 + d] = v;
        u16[(size_t)b * 128 + d] = f2bf(v);
    }
}

// ---------------- final: bf16 MFMA LSE partials, LDS-staged B panel ----------------
// grid (NT2, 2): block stages c16 panel [128 rows x 128 k] in LDS once (XOR-swizzled),
// then loops 8 m-tiles of 128 rows. B read from HBM exactly twice total.
__global__ __launch_bounds__(512) void lse_mfma(const short* __restrict__ u16,
                                                const short* __restrict__ c16,
                                                float* __restrict__ pm, float* __restrict__ ps) {
    __shared__ short Bs[128 * 128];   // 32 KB
    int n0 = blockIdx.x * 128;
    int tid = threadIdx.x;
    // stage: 2048 16B chunks, coalesced global, swizzled LDS (chunk cc ^= row&7)
    const uint4* gsrc = (const uint4*)&c16[(size_t)n0 * 128];
#pragma unroll
    for (int j = 0; j < 4; ++j) {
        int c = j * 512 + tid;
        int r = c >> 4, cc = c & 15;
        *(uint4*)((char*)Bs + r * 256 + ((cc ^ (r & 7)) << 4)) = gsrc[c];
    }
    __syncthreads();

    int w = tid >> 6;           // 8 waves: 16-row strip of each m-tile
    int lane = tid & 63;
    int la = lane & 15, lb = lane >> 4;
    for (int mt = blockIdx.y * 8; mt < blockIdx.y * 8 + 8; ++mt) {
        int m_a = mt * 128 + w * 16 + la;
        f32x4 acc[8] = {};
#pragma unroll
        for (int kc = 0; kc < 4; ++kc) {
            short8 af = *(const short8*)&u16[(size_t)m_a * 128 + kc * 32 + lb * 8];
#pragma unroll
            for (int s = 0; s < 8; ++s) {
                int nl = s * 16 + la;
                short8 bf = *(const short8*)((const char*)Bs + nl * 256 +
                                             (((kc * 4 + lb) ^ (nl & 7)) << 4));
                acc[s] = __builtin_amdgcn_mfma_f32_16x16x32_bf16(af, bf, acc[s], 0, 0, 0);
            }
        }
#pragma unroll
        for (int r = 0; r < 4; ++r) {
            int row = mt * 128 + w * 16 + lb * 4 + r;
            float mx = -3.4e38f;
#pragma unroll
            for (int s = 0; s < 8; ++s)
                if (n0 + s * 16 + la < COMPN) mx = fmaxf(mx, acc[s][r]);
#pragma unroll
            for (int off = 1; off < 16; off <<= 1) mx = fmaxf(mx, __shfl_xor(mx, off));
            float sm = 0.f;
#pragma unroll
            for (int s = 0; s < 8; ++s)
                if (n0 + s * 16 + la < COMPN) sm += __expf(acc[s][r] - mx);
#pragma unroll
            for (int off = 1; off < 16; off <<= 1) sm += __shfl_xor(sm, off);
            if (la == 0) {
                pm[(size_t)blockIdx.x * BB + row] = mx;
                ps[(size_t)blockIdx.x * BB + row] = sm;
            }
        }
    }
}

// ---------------- final: merge per-tile partials ----------------
__global__ void lse_merge(const float* __restrict__ pm, const float* __restrict__ ps,
                          float* __restrict__ lse_row) {
    int row = blockIdx.x * 256 + threadIdx.x;
    float m = -3.4e38f, s = 0.f;
    for (int c = 0; c < NT2; ++c) {
        float mi = pm[(size_t)c * BB + row];
        float si = ps[(size_t)c * BB + row];
        if (mi > m) { s = s * __expf(m - mi) + si; m = mi; }
        else        { s += si * __expf(mi - m); }
    }
    lse_row[row] = m + logf(s);
}

// ---------------- final: loss ----------------
__global__ void final_k(const float* __restrict__ u_emb, const float* __restrict__ ent,
                        const int* __restrict__ crel, const float* __restrict__ lse_row,
                        float* __restrict__ out) {
    int b = blockIdx.x * 256 + threadIdx.x;
    if (b >= BB) return;
    float lse = lse_row[b];
    const float* u = &u_emb[(size_t)b * 128];
    const float* c = &ent[(size_t)(USERN + crel[b]) * 128];
    float pos = 0.f;
#pragma unroll
    for (int k = 0; k < 128; k += 4) {
        float4 uv = *(const float4*)&u[k];
        float4 cv = *(const float4*)&c[k];
        pos += uv.x * cv.x + uv.y * cv.y + uv.z * cv.z + uv.w * cv.w;
    }
    atomicAdd(out, lse - pos);
}

extern "C" void kernel_launch(void* const* d_in, const int* in_sizes, int n_in,
                              void* d_out, int out_size, void* d_ws, size_t ws_size,
                              hipStream_t stream) {
    const float* ent  = (const float*)d_in[0];
    const float* c0   = (const float*)d_in[1];
    const float* Wih  = (const float*)d_in[2];
    const float* Whh  = (const float*)d_in[3];
    const float* bih  = (const float*)d_in[4];
    const float* bhh  = (const float*)d_in[5];
    const int* esrc   = (const int*)d_in[6];
    const int* edst   = (const int*)d_in[7];
    const int* act    = (const int*)d_in[8];
    const int* susr   = (const int*)d_in[9];
    const int* stime  = (const int*)d_in[10];
    const int* crel   = (const int*)d_in[11];
    float* out = (float*)d_out;

    float* ws = (float*)d_ws;
    size_t o = 0;
    float* node  = ws + o; o += (size_t)NNODE * EMBD;
    float* cxp   = ws + o; o += (size_t)NNODE * EMBD;
    float* msg   = ws + o; o += (size_t)NNODE * EMBD;
    float* u_emb = ws + o; o += (size_t)BB * 128;
    float* lse_row = ws + o; o += (size_t)BB;
    float* cnt   = ws + o; o += (size_t)NNODE;
    short* xh16  = (short*)(ws + o); o += (size_t)AA * 256 / 2;
    short* w16   = (short*)(ws + o); o += (size_t)512 * 256 / 2;
    float* bsum  = ws + o; o += 512;
    short* c16   = (short*)(ws + o); o += (size_t)NPAD * 128 / 2;
    short* u16   = (short*)(ws + o); o += (size_t)BB * 128 / 2;
    // lse partials reuse msg (idle post-loop; re-zeroed by init each launch)
    float* pm = msg;
    float* ps = msg + (size_t)NT2 * BB;

    init_kernel<<<2048, 256, 0, stream>>>((const float4*)ent, (const float4*)c0,
                                          (float4*)node, (float4*)cxp, (float4*)msg, cnt, out);
    convert_kernel<<<2048, 256, 0, stream>>>(Wih, Whh, bih, bhh, ent, w16, bsum, c16);

    for (int t = 0; t < TT; ++t) {
        const int* src_t = esrc + (size_t)t * EE;
        const int* dst_t = edst + (size_t)t * EE;
        const int* act_t = act + (size_t)t * AA;
        edge_kernel<<<EE / 2, 256, 0, stream>>>(src_t, dst_t, node, msg, cnt);
        build_xh<<<AA / 4, 512, 0, stream>>>(act_t, node, msg, cnt, xh16);
        apply_kernel<<<NNODE / 2, 256, 0, stream>>>(node, msg, cnt);
        gates_mfma<<<128, 512, 0, stream>>>(xh16, w16, bsum, act_t, node, cxp);
        snapshot_k<<<BB / 2, 256, 0, stream>>>(node, susr, stime, u_emb, u16, t);
    }

    lse_mfma<<<dim3(NT2, 2), 512, 0, stream>>>(u16, c16, pm, ps);
    lse_merge<<<BB / 256, 256, 0, stream>>>(pm, ps, lse_row);
    final_k<<<BB / 256, 256, 0, stream>>>(u_emb, ent, crel, lse_row, out);
}

// Round 6
// 2949.278 us; speedup vs baseline: 1.7252x; 1.4248x over previous
//
#include <hip/hip_runtime.h>
#include <hip/hip_bf16.h>
#include <math.h>

#define NNODE 200000
#define EMBD  128
#define TT    32
#define EE    100000
#define AA    4096
#define BB    2048
#define USERN 150000
#define COMPN 49998
#define NPAD  50048   // 391*128
#define NT2   391     // lse n-tiles of 128
#define NT2P  392     // padded stride for partials

typedef __attribute__((ext_vector_type(8))) short short8;
typedef __attribute__((ext_vector_type(4))) float f32x4;

__device__ __forceinline__ short f2bf(float f) {
    unsigned u = __float_as_uint(f);
    unsigned r = (u + 0x7fffu + ((u >> 16) & 1u)) >> 16;   // RNE
    return (short)r;
}
__device__ __forceinline__ unsigned pack2bf(float lo, float hi) {
    return ((unsigned)(unsigned short)f2bf(hi) << 16) | (unsigned)(unsigned short)f2bf(lo);
}
__device__ __forceinline__ float bflo(unsigned p) { return __uint_as_float(p << 16); }
__device__ __forceinline__ float bfhi(unsigned p) { return __uint_as_float(p & 0xffff0000u); }
__device__ __forceinline__ float sig(float x) { return 1.f / (1.f + __expf(-x)); }
__device__ __forceinline__ void atomic_pk_add_bf16(unsigned* addr, unsigned val) {
    asm volatile("global_atomic_pk_add_bf16 %0, %1, off" :: "v"(addr), "v"(val) : "memory");
}

// ---------------- init ----------------
__global__ void init_kernel(const float4* __restrict__ ent, const float4* __restrict__ c0,
                            float4* __restrict__ node, float4* __restrict__ cxp,
                            uint4* __restrict__ msgu, float* __restrict__ cnt,
                            float* __restrict__ out) {
    const long NV = (long)NNODE * EMBD / 4;       // 6.4M float4
    const long NM = (long)NNODE * EMBD * 2 / 16;  // 3.2M uint4 (bf16 msg)
    long i0 = (long)blockIdx.x * blockDim.x + threadIdx.x;
    long stride = (long)gridDim.x * blockDim.x;
    uint4 z4 = make_uint4(0u, 0u, 0u, 0u);
    for (long i = i0; i < NV; i += stride) { node[i] = ent[i]; cxp[i] = c0[i]; }
    for (long i = i0; i < NM; i += stride) msgu[i] = z4;
    for (long i = i0; i < NNODE; i += stride) cnt[i] = 0.f;
    if (i0 == 0) out[0] = 0.f;
}

// ---------------- once: convert W (gate-concat), biases, comp embeddings to bf16 ----------------
__global__ void convert_kernel(const float* __restrict__ Wih, const float* __restrict__ Whh,
                               const float* __restrict__ bih, const float* __restrict__ bhh,
                               const float* __restrict__ ent,
                               short* __restrict__ w16, float* __restrict__ bsum,
                               short* __restrict__ c16) {
    long i0 = (long)blockIdx.x * blockDim.x + threadIdx.x;
    long stride = (long)gridDim.x * blockDim.x;
    for (long i = i0; i < 512 * 256; i += stride) {
        int n = i >> 8, k = i & 255;
        float v = (k < 128) ? Wih[(size_t)n * 128 + k] : Whh[(size_t)n * 128 + (k - 128)];
        w16[i] = f2bf(v);
    }
    for (long i = i0; i < 512; i += stride) bsum[i] = bih[i] + bhh[i];
    for (long i = i0; i < (long)NPAD * 128; i += stride) {
        long r = i >> 7;
        float v = (r < COMPN) ? ent[(size_t)(USERN + r) * 128 + (i & 127)] : 0.f;
        c16[i] = f2bf(v);
    }
}

// ---------------- per-step: edge scatter (bf16 packed atomics) ----------------
__global__ __launch_bounds__(256) void edge_kernel(const int* __restrict__ src,
                                                   const int* __restrict__ dst,
                                                   const float* __restrict__ node,
                                                   unsigned* __restrict__ msgu,
                                                   float* __restrict__ cnt) {
    int e = blockIdx.x * 4 + (threadIdx.x >> 6);
    int lane = threadIdx.x & 63;
    int s = src[e];
    int v = dst[e];
    float2 x = *(const float2*)&node[(size_t)s * 128 + lane * 2];
    atomic_pk_add_bf16(&msgu[(size_t)v * 64 + lane], pack2bf(x.x, x.y));
    if (lane == 0) atomicAdd(&cnt[v], 1.0f);
}

// ---------------- per-step: build xh16 = [x | prev_h] bf16 (pre-update gather) ----------------
__global__ __launch_bounds__(512) void build_xh(const int* __restrict__ act, const float* __restrict__ node,
                                                const unsigned* __restrict__ msgu,
                                                const float* __restrict__ cnt,
                                                short* __restrict__ xh16) {
    int a = blockIdx.x * 4 + (threadIdx.x >> 7);
    int d = threadIdx.x & 127;
    int v = act[a];
    float ph = node[(size_t)v * 128 + d];
    float c = cnt[v];
    unsigned p = msgu[(size_t)v * 64 + (d >> 1)];
    float mv = (d & 1) ? bfhi(p) : bflo(p);
    float ag = (c > 0.f) ? mv / c : 0.f;
    xh16[(size_t)a * 256 + d] = f2bf(ph + ag);
    xh16[(size_t)a * 256 + 128 + d] = f2bf(ph);
}

// ---------------- per-step: apply agg to node, re-zero msg/cnt ----------------
__global__ __launch_bounds__(512) void apply_kernel(float* __restrict__ node,
                                                    unsigned* __restrict__ msgu,
                                                    float* __restrict__ cnt) {
    int v = blockIdx.x * 8 + (threadIdx.x >> 6);
    int lane = threadIdx.x & 63;
    float c = cnt[v];
    if (c > 0.f) {
        unsigned p = msgu[(size_t)v * 64 + lane];
        float rc = 1.f / c;
        float2* np = (float2*)&node[(size_t)v * 128 + lane * 2];
        float2 nv = *np;
        nv.x += bflo(p) * rc;
        nv.y += bfhi(p) * rc;
        *np = nv;
        msgu[(size_t)v * 64 + lane] = 0u;
        if (lane == 0) cnt[v] = 0.f;
    }
}

// ---------------- per-step: MFMA gates + fused LSTM epilogue ----------------
__global__ __launch_bounds__(512) void gates_mfma(const short* __restrict__ xh16,
                                                  const short* __restrict__ w16,
                                                  const float* __restrict__ bsum,
                                                  const int* __restrict__ act_t,
                                                  float* __restrict__ node, float* __restrict__ cxp) {
    int m0 = blockIdx.x * 32;
    int tid = threadIdx.x;
    int w = tid >> 6;           // wave 0..7
    int wm = w >> 2;            // m-subtile 0..1
    int cg = w & 3;             // d-column group (32 wide)
    int lane = tid & 63;
    int la = lane & 15, lb = lane >> 4;
    int m_a = m0 + wm * 16 + la;
    f32x4 acc[8] = {};
#pragma unroll
    for (int kc = 0; kc < 8; ++kc) {
        short8 af = *(const short8*)&xh16[(size_t)m_a * 256 + kc * 32 + lb * 8];
#pragma unroll
        for (int s = 0; s < 8; ++s) {
            int n = (s & 3) * 128 + cg * 32 + (s >> 2) * 16 + la;
            short8 bf = *(const short8*)&w16[(size_t)n * 256 + kc * 32 + lb * 8];
            acc[s] = __builtin_amdgcn_mfma_f32_16x16x32_bf16(af, bf, acc[s], 0, 0, 0);
        }
    }
#pragma unroll
    for (int half = 0; half < 2; ++half) {
        int d = cg * 32 + half * 16 + la;
        float b_i = bsum[d], b_f = bsum[128 + d], b_g = bsum[256 + d], b_o = bsum[384 + d];
#pragma unroll
        for (int r = 0; r < 4; ++r) {
            int row = m0 + wm * 16 + lb * 4 + r;
            int v = act_t[row];
            float gi = acc[half * 4 + 0][r] + b_i;
            float gf = acc[half * 4 + 1][r] + b_f;
            float gg = acc[half * 4 + 2][r] + b_g;
            float go = acc[half * 4 + 3][r] + b_o;
            float pc = cxp[(size_t)v * 128 + d];
            float c_ = sig(gf) * pc + sig(gi) * tanhf(gg);
            float h_ = sig(go) * tanhf(c_);
            node[(size_t)v * 128 + d] = h_;
            cxp[(size_t)v * 128 + d] = c_;
        }
    }
}

// ---------------- per-step: snapshot rows whose seed_time == t ----------------
__global__ void snapshot_k(const float* __restrict__ node, const int* __restrict__ su,
                           const int* __restrict__ st, float* __restrict__ u_emb,
                           short* __restrict__ u16, int t) {
    int b = blockIdx.x * 2 + threadIdx.x / 128;
    int d = threadIdx.x % 128;
    if (st[b] == t) {
        float v = node[(size_t)su[b] * 128 + d];
        u_emb[(size_t)b * 128 + d] = v;
        u16[(size_t)b * 128 + d] = f2bf(v);
    }
}

// ---------------- final: bf16 MFMA LSE partials, LDS-staged B panel ----------------
__global__ __launch_bounds__(512) void lse_mfma(const short* __restrict__ u16,
                                                const short* __restrict__ c16,
                                                float* __restrict__ pm, float* __restrict__ ps) {
    __shared__ short Bs[128 * 128];   // 32 KB
    int n0 = blockIdx.x * 128;
    int tid = threadIdx.x;
    const uint4* gsrc = (const uint4*)&c16[(size_t)n0 * 128];
#pragma unroll
    for (int j = 0; j < 4; ++j) {
        int c = j * 512 + tid;
        int r = c >> 4, cc = c & 15;
        *(uint4*)((char*)Bs + r * 256 + ((cc ^ (r & 7)) << 4)) = gsrc[c];
    }
    __syncthreads();

    int w = tid >> 6;
    int lane = tid & 63;
    int la = lane & 15, lb = lane >> 4;
    for (int mt = blockIdx.y * 8; mt < blockIdx.y * 8 + 8; ++mt) {
        int m_a = mt * 128 + w * 16 + la;
        f32x4 acc[8] = {};
#pragma unroll
        for (int kc = 0; kc < 4; ++kc) {
            short8 af = *(const short8*)&u16[(size_t)m_a * 128 + kc * 32 + lb * 8];
#pragma unroll
            for (int s = 0; s < 8; ++s) {
                int nl = s * 16 + la;
                short8 bf = *(const short8*)((const char*)Bs + nl * 256 +
                                             (((kc * 4 + lb) ^ (nl & 7)) << 4));
                acc[s] = __builtin_amdgcn_mfma_f32_16x16x32_bf16(af, bf, acc[s], 0, 0, 0);
            }
        }
#pragma unroll
        for (int r = 0; r < 4; ++r) {
            int row = mt * 128 + w * 16 + lb * 4 + r;
            float mx = -3.4e38f;
#pragma unroll
            for (int s = 0; s < 8; ++s)
                if (n0 + s * 16 + la < COMPN) mx = fmaxf(mx, acc[s][r]);
#pragma unroll
            for (int off = 1; off < 16; off <<= 1) mx = fmaxf(mx, __shfl_xor(mx, off));
            float sm = 0.f;
#pragma unroll
            for (int s = 0; s < 8; ++s)
                if (n0 + s * 16 + la < COMPN) sm += __expf(acc[s][r] - mx);
#pragma unroll
            for (int off = 1; off < 16; off <<= 1) sm += __shfl_xor(sm, off);
            if (la == 0) {
                pm[(size_t)row * NT2P + blockIdx.x] = mx;
                ps[(size_t)row * NT2P + blockIdx.x] = sm;
            }
        }
    }
}

// ---------------- final: wave-per-row merge + pos dot + loss ----------------
__global__ __launch_bounds__(256) void merge_final(const float* __restrict__ pm,
                                                   const float* __restrict__ ps,
                                                   const float* __restrict__ u_emb,
                                                   const float* __restrict__ ent,
                                                   const int* __restrict__ crel,
                                                   float* __restrict__ out) {
    int row = blockIdx.x * 4 + (threadIdx.x >> 6);
    int lane = threadIdx.x & 63;
    float m = -3.4e38f, s = 0.f;
    for (int c = lane; c < NT2; c += 64) {
        float mi = pm[(size_t)row * NT2P + c];
        float si = ps[(size_t)row * NT2P + c];
        float mn = fmaxf(m, mi);
        s = s * __expf(m - mn) + si * __expf(mi - mn);
        m = mn;
    }
#pragma unroll
    for (int off = 1; off < 64; off <<= 1) {
        float mo = __shfl_xor(m, off);
        float so = __shfl_xor(s, off);
        float mn = fmaxf(m, mo);
        s = s * __expf(m - mn) + so * __expf(mo - mn);
        m = mn;
    }
    float2 uv = *(const float2*)&u_emb[(size_t)row * 128 + lane * 2];
    float2 cv = *(const float2*)&ent[(size_t)(USERN + crel[row]) * 128 + lane * 2];
    float p = uv.x * cv.x + uv.y * cv.y;
#pragma unroll
    for (int off = 1; off < 64; off <<= 1) p += __shfl_xor(p, off);
    if (lane == 0) atomicAdd(out, m + logf(s) - p);
}

extern "C" void kernel_launch(void* const* d_in, const int* in_sizes, int n_in,
                              void* d_out, int out_size, void* d_ws, size_t ws_size,
                              hipStream_t stream) {
    const float* ent  = (const float*)d_in[0];
    const float* c0   = (const float*)d_in[1];
    const float* Wih  = (const float*)d_in[2];
    const float* Whh  = (const float*)d_in[3];
    const float* bih  = (const float*)d_in[4];
    const float* bhh  = (const float*)d_in[5];
    const int* esrc   = (const int*)d_in[6];
    const int* edst   = (const int*)d_in[7];
    const int* act    = (const int*)d_in[8];
    const int* susr   = (const int*)d_in[9];
    const int* stime  = (const int*)d_in[10];
    const int* crel   = (const int*)d_in[11];
    float* out = (float*)d_out;

    float* ws = (float*)d_ws;
    size_t o = 0;
    float* node  = ws + o; o += (size_t)NNODE * EMBD;
    float* cxp   = ws + o; o += (size_t)NNODE * EMBD;
    unsigned* msgu = (unsigned*)(ws + o); o += (size_t)NNODE * EMBD / 2;  // bf16 msg (51.2MB)
    float* u_emb = ws + o; o += (size_t)BB * 128;
    float* cnt   = ws + o; o += (size_t)NNODE;
    short* xh16  = (short*)(ws + o); o += (size_t)AA * 256 / 2;
    short* w16   = (short*)(ws + o); o += (size_t)512 * 256 / 2;
    float* bsum  = ws + o; o += 512;
    short* c16   = (short*)(ws + o); o += (size_t)NPAD * 128 / 2;
    short* u16   = (short*)(ws + o); o += (size_t)BB * 128 / 2;
    // lse partials reuse msg region (idle post-loop)
    float* pm = (float*)msgu;
    float* ps = pm + (size_t)BB * NT2P;

    init_kernel<<<2048, 256, 0, stream>>>((const float4*)ent, (const float4*)c0,
                                          (float4*)node, (float4*)cxp, (uint4*)msgu, cnt, out);
    convert_kernel<<<2048, 256, 0, stream>>>(Wih, Whh, bih, bhh, ent, w16, bsum, c16);

    for (int t = 0; t < TT; ++t) {
        const int* src_t = esrc + (size_t)t * EE;
        const int* dst_t = edst + (size_t)t * EE;
        const int* act_t = act + (size_t)t * AA;
        edge_kernel<<<EE / 4, 256, 0, stream>>>(src_t, dst_t, node, msgu, cnt);
        build_xh<<<AA / 4, 512, 0, stream>>>(act_t, node, msgu, cnt, xh16);
        apply_kernel<<<NNODE / 8, 512, 0, stream>>>(node, msgu, cnt);
        gates_mfma<<<128, 512, 0, stream>>>(xh16, w16, bsum, act_t, node, cxp);
        snapshot_k<<<BB / 2, 256, 0, stream>>>(node, susr, stime, u_emb, u16, t);
    }

    lse_mfma<<<dim3(NT2, 2), 512, 0, stream>>>(u16, c16, pm, ps);
    merge_final<<<BB / 4, 256, 0, stream>>>(pm, ps, u_emb, ent, crel, out);
}

// Round 8
// 2345.787 us; speedup vs baseline: 2.1691x; 1.2573x over previous
//
#include <hip/hip_runtime.h>
#include <hip/hip_bf16.h>
#include <math.h>

#define NNODE 200000
#define EMBD  128
#define TT    32
#define EE    100000
#define AA    4096
#define BB    2048
#define USERN 150000
#define COMPN 49998
#define NPAD  50048   // 391*128
#define NT2   391     // lse n-tiles of 128
#define NT2P  392     // padded stride for partials

typedef __attribute__((ext_vector_type(8))) short short8;
typedef __attribute__((ext_vector_type(4))) float f32x4;

__device__ __forceinline__ unsigned short f2bf(float f) {
    unsigned u = __float_as_uint(f);
    unsigned r = (u + 0x7fffu + ((u >> 16) & 1u)) >> 16;   // RNE
    return (unsigned short)r;
}
__device__ __forceinline__ unsigned pack2bf(float lo, float hi) {
    return ((unsigned)f2bf(hi) << 16) | (unsigned)f2bf(lo);
}
__device__ __forceinline__ float bflo(unsigned p) { return __uint_as_float(p << 16); }
__device__ __forceinline__ float bfhi(unsigned p) { return __uint_as_float(p & 0xffff0000u); }
__device__ __forceinline__ float bf2f(unsigned short b) { return __uint_as_float((unsigned)b << 16); }
__device__ __forceinline__ float sig(float x) { return 1.f / (1.f + __expf(-x)); }
__device__ __forceinline__ void atomic_pk_add_bf16(unsigned* addr, unsigned val) {
    asm volatile("global_atomic_pk_add_bf16 %0, %1, off" :: "v"(addr), "v"(val) : "memory");
}

// ---------------- init: node16 = bf16(ent), msg/cnt/stamp/out zero (NO cxp copy) ----------------
__global__ void init_kernel(const float4* __restrict__ ent, unsigned short* __restrict__ node16,
                            uint4* __restrict__ msgu4, float* __restrict__ cnt,
                            int* __restrict__ stamp, float* __restrict__ out) {
    const long NV = (long)NNODE * EMBD / 4;        // 6.4M float4 of ent
    const long NM = (long)NNODE * EMBD / 8;        // 3.2M uint4 of msg (bf16)
    long i0 = (long)blockIdx.x * blockDim.x + threadIdx.x;
    long stride = (long)gridDim.x * blockDim.x;
    uint2* n2 = (uint2*)node16;
    for (long i = i0; i < NV; i += stride) {
        float4 v = ent[i];
        n2[i] = make_uint2(pack2bf(v.x, v.y), pack2bf(v.z, v.w));
    }
    uint4 z4 = make_uint4(0u, 0u, 0u, 0u);
    for (long i = i0; i < NM; i += stride) msgu4[i] = z4;
    for (long i = i0; i < NNODE; i += stride) { cnt[i] = 0.f; stamp[i] = 0; }
    if (i0 == 0) out[0] = 0.f;
}

// ---------------- once: convert W (gate-concat), biases, comp embeddings to bf16 ----------------
__global__ void convert_kernel(const float* __restrict__ Wih, const float* __restrict__ Whh,
                               const float* __restrict__ bih, const float* __restrict__ bhh,
                               const float* __restrict__ ent,
                               short* __restrict__ w16, float* __restrict__ bsum,
                               short* __restrict__ c16) {
    long i0 = (long)blockIdx.x * blockDim.x + threadIdx.x;
    long stride = (long)gridDim.x * blockDim.x;
    for (long i = i0; i < 512 * 256; i += stride) {
        int n = i >> 8, k = i & 255;
        float v = (k < 128) ? Wih[(size_t)n * 128 + k] : Whh[(size_t)n * 128 + (k - 128)];
        w16[i] = (short)f2bf(v);
    }
    for (long i = i0; i < 512; i += stride) bsum[i] = bih[i] + bhh[i];
    for (long i = i0; i < (long)NPAD * 128; i += stride) {
        long r = i >> 7;
        float v = (r < COMPN) ? ent[(size_t)(USERN + r) * 128 + (i & 127)] : 0.f;
        c16[i] = (short)f2bf(v);
    }
}

// ---------------- per-step: edge scatter (bf16 bits, no conversion) || snapshot(t-1) ----------------
__global__ __launch_bounds__(256) void edge_snap(const int* __restrict__ src,
                                                 const int* __restrict__ dst,
                                                 const unsigned short* __restrict__ node16,
                                                 unsigned* __restrict__ msgu,
                                                 float* __restrict__ cnt,
                                                 const int* __restrict__ su,
                                                 const int* __restrict__ st,
                                                 float* __restrict__ u_emb,
                                                 unsigned short* __restrict__ u16, int t) {
    int blk = blockIdx.x;
    int tid = threadIdx.x;
    if (blk < EE / 4) {
        int e = blk * 4 + (tid >> 6);
        int lane = tid & 63;
        int s = src[e];
        int v = dst[e];
        unsigned pair = ((const unsigned*)node16)[(size_t)s * 64 + lane];
        atomic_pk_add_bf16(&msgu[(size_t)v * 64 + lane], pair);
        if (lane == 0) atomicAdd(&cnt[v], 1.0f);
    } else {
        if (t == 0) return;
        int b = (blk - EE / 4) * 2 + tid / 128;
        int d = tid % 128;
        if (st[b] == t - 1) {
            unsigned short hv = node16[(size_t)su[b] * 128 + d];
            u16[(size_t)b * 128 + d] = hv;
            u_emb[(size_t)b * 128 + d] = bf2f(hv);
        }
    }
}

// ---------------- per-step: fused [build xh in LDS + MFMA gates + LSTM epilogue] ----------------
// Runs BEFORE apply: reads pre-update node (prev_h), computes x = node + msg/cnt itself,
// writes h/c, zeroes msg/cnt for act rows (so apply skips them via c==0), lazy-inits cxp via stamp.
__global__ __launch_bounds__(512) void gates_mfma(unsigned short* node16, unsigned* msgu,
                                                  float* cnt,
                                                  const short* __restrict__ w16,
                                                  const float* __restrict__ bsum,
                                                  const int* __restrict__ act_t,
                                                  float* cxp, const float* __restrict__ c0,
                                                  int* __restrict__ stamp, int t) {
    __shared__ unsigned short XH[16 * 256];   // 8 KB, XOR-swizzled 16B chunks
    __shared__ int PREV[16];
    int m0 = blockIdx.x * 16;
    int tid = threadIdx.x;
    {   // build phase: 16 rows x 32 chunks (x: 0..15, h: 16..31)
        int row = tid >> 5, j = tid & 31;
        int v = act_t[m0 + row];
        if (j == 0) PREV[row] = stamp[v];
        int ch = j & 15;
        int sw = ch ^ (row & 7);
        uint4 nd = *(const uint4*)(node16 + (size_t)v * 128 + ch * 8);
        if (j < 16) {
            float c = cnt[v];
            float rc = (c > 0.f) ? 1.f / c : 0.f;
            uint4 mg = *(const uint4*)(msgu + (size_t)v * 64 + ch * 4);
            uint4 xx;
            xx.x = pack2bf(bflo(nd.x) + bflo(mg.x) * rc, bfhi(nd.x) + bfhi(mg.x) * rc);
            xx.y = pack2bf(bflo(nd.y) + bflo(mg.y) * rc, bfhi(nd.y) + bfhi(mg.y) * rc);
            xx.z = pack2bf(bflo(nd.z) + bflo(mg.z) * rc, bfhi(nd.z) + bfhi(mg.z) * rc);
            xx.w = pack2bf(bflo(nd.w) + bflo(mg.w) * rc, bfhi(nd.w) + bfhi(mg.w) * rc);
            *(uint4*)((char*)XH + row * 512 + (sw << 4)) = xx;
        } else {
            *(uint4*)((char*)XH + row * 512 + ((16 + sw) << 4)) = nd;   // prev_h
        }
    }
    __syncthreads();
    int w = tid >> 6, lane = tid & 63;
    int la = lane & 15, lb = lane >> 4;
    f32x4 acc[4] = {};
#pragma unroll
    for (int kc = 0; kc < 8; ++kc) {
        int cc = kc * 4 + lb;
        int sc = (cc & 16) | ((cc & 15) ^ (la & 7));
        short8 af = *(const short8*)((char*)XH + la * 512 + (sc << 4));
#pragma unroll
        for (int s = 0; s < 4; ++s) {
            int n = s * 128 + w * 16 + la;
            short8 bf = *(const short8*)&w16[(size_t)n * 256 + kc * 32 + lb * 8];
            acc[s] = __builtin_amdgcn_mfma_f32_16x16x32_bf16(af, bf, acc[s], 0, 0, 0);
        }
    }
    int d = w * 16 + la;
    float b_i = bsum[d], b_f = bsum[128 + d], b_g = bsum[256 + d], b_o = bsum[384 + d];
#pragma unroll
    for (int r = 0; r < 4; ++r) {
        int lrow = lb * 4 + r;
        int v = act_t[m0 + lrow];
        float gi = acc[0][r] + b_i;
        float gf = acc[1][r] + b_f;
        float gg = acc[2][r] + b_g;
        float go = acc[3][r] + b_o;
        float pc = PREV[lrow] ? cxp[(size_t)v * 128 + d] : c0[(size_t)v * 128 + d];
        float c_ = sig(gf) * pc + sig(gi) * tanhf(gg);
        float h_ = sig(go) * tanhf(c_);
        node16[(size_t)v * 128 + d] = f2bf(h_);
        cxp[(size_t)v * 128 + d] = c_;
        msgu[(size_t)v * 64 + (d >> 1)] = 0u;
        if (d == 0) { cnt[v] = 0.f; stamp[v] = t + 1; }
    }
}

// ---------------- per-step: apply agg to non-act touched rows (act rows have c==0) ----------------
__global__ __launch_bounds__(512) void apply_kernel(unsigned short* node16,
                                                    unsigned* msgu, float* cnt) {
    int v = blockIdx.x * 8 + (threadIdx.x >> 6);
    int lane = threadIdx.x & 63;
    float c = cnt[v];
    if (c > 0.f) {
        unsigned p = msgu[(size_t)v * 64 + lane];
        unsigned n = ((unsigned*)node16)[(size_t)v * 64 + lane];
        float rc = 1.f / c;
        ((unsigned*)node16)[(size_t)v * 64 + lane] =
            pack2bf(bflo(n) + bflo(p) * rc, bfhi(n) + bfhi(p) * rc);
        msgu[(size_t)v * 64 + lane] = 0u;
        if (lane == 0) cnt[v] = 0.f;
    }
}

// ---------------- post-loop: snapshot t=31 ----------------
__global__ __launch_bounds__(256) void snap31(const unsigned short* __restrict__ node16,
                                              const int* __restrict__ su,
                                              const int* __restrict__ st,
                                              float* __restrict__ u_emb,
                                              unsigned short* __restrict__ u16) {
    int b = blockIdx.x * 2 + threadIdx.x / 128;
    int d = threadIdx.x % 128;
    if (st[b] == TT - 1) {
        unsigned short hv = node16[(size_t)su[b] * 128 + d];
        u16[(size_t)b * 128 + d] = hv;
        u_emb[(size_t)b * 128 + d] = bf2f(hv);
    }
}

// ---------------- final: bf16 MFMA LSE partials, LDS-staged B panel ----------------
__global__ __launch_bounds__(512) void lse_mfma(const short* __restrict__ u16,
                                                const short* __restrict__ c16,
                                                float* __restrict__ pm, float* __restrict__ ps) {
    __shared__ short Bs[128 * 128];   // 32 KB
    int n0 = blockIdx.x * 128;
    int tid = threadIdx.x;
    const uint4* gsrc = (const uint4*)&c16[(size_t)n0 * 128];
#pragma unroll
    for (int j = 0; j < 4; ++j) {
        int c = j * 512 + tid;
        int r = c >> 4, cc = c & 15;
        *(uint4*)((char*)Bs + r * 256 + ((cc ^ (r & 7)) << 4)) = gsrc[c];
    }
    __syncthreads();

    int w = tid >> 6;
    int lane = tid & 63;
    int la = lane & 15, lb = lane >> 4;
    for (int mt = blockIdx.y * 8; mt < blockIdx.y * 8 + 8; ++mt) {
        int m_a = mt * 128 + w * 16 + la;
        f32x4 acc[8] = {};
#pragma unroll
        for (int kc = 0; kc < 4; ++kc) {
            short8 af = *(const short8*)&u16[(size_t)m_a * 128 + kc * 32 + lb * 8];
#pragma unroll
            for (int s = 0; s < 8; ++s) {
                int nl = s * 16 + la;
                short8 bf = *(const short8*)((const char*)Bs + nl * 256 +
                                             (((kc * 4 + lb) ^ (nl & 7)) << 4));
                acc[s] = __builtin_amdgcn_mfma_f32_16x16x32_bf16(af, bf, acc[s], 0, 0, 0);
            }
        }
#pragma unroll
        for (int r = 0; r < 4; ++r) {
            int row = mt * 128 + w * 16 + lb * 4 + r;
            float mx = -3.4e38f;
#pragma unroll
            for (int s = 0; s < 8; ++s)
                if (n0 + s * 16 + la < COMPN) mx = fmaxf(mx, acc[s][r]);
#pragma unroll
            for (int off = 1; off < 16; off <<= 1) mx = fmaxf(mx, __shfl_xor(mx, off));
            float sm = 0.f;
#pragma unroll
            for (int s = 0; s < 8; ++s)
                if (n0 + s * 16 + la < COMPN) sm += __expf(acc[s][r] - mx);
#pragma unroll
            for (int off = 1; off < 16; off <<= 1) sm += __shfl_xor(sm, off);
            if (la == 0) {
                pm[(size_t)row * NT2P + blockIdx.x] = mx;
                ps[(size_t)row * NT2P + blockIdx.x] = sm;
            }
        }
    }
}

// ---------------- final: wave-per-row merge + pos dot + loss ----------------
__global__ __launch_bounds__(256) void merge_final(const float* __restrict__ pm,
                                                   const float* __restrict__ ps,
                                                   const float* __restrict__ u_emb,
                                                   const float* __restrict__ ent,
                                                   const int* __restrict__ crel,
                                                   float* __restrict__ out) {
    int row = blockIdx.x * 4 + (threadIdx.x >> 6);
    int lane = threadIdx.x & 63;
    float m = -3.4e38f, s = 0.f;
    for (int c = lane; c < NT2; c += 64) {
        float mi = pm[(size_t)row * NT2P + c];
        float si = ps[(size_t)row * NT2P + c];
        float mn = fmaxf(m, mi);
        s = s * __expf(m - mn) + si * __expf(mi - mn);
        m = mn;
    }
#pragma unroll
    for (int off = 1; off < 64; off <<= 1) {
        float mo = __shfl_xor(m, off);
        float so = __shfl_xor(s, off);
        float mn = fmaxf(m, mo);
        s = s * __expf(m - mn) + so * __expf(mo - mn);
        m = mn;
    }
    float2 uv = *(const float2*)&u_emb[(size_t)row * 128 + lane * 2];
    float2 cv = *(const float2*)&ent[(size_t)(USERN + crel[row]) * 128 + lane * 2];
    float p = uv.x * cv.x + uv.y * cv.y;
#pragma unroll
    for (int off = 1; off < 64; off <<= 1) p += __shfl_xor(p, off);
    if (lane == 0) atomicAdd(out, m + logf(s) - p);
}

extern "C" void kernel_launch(void* const* d_in, const int* in_sizes, int n_in,
                              void* d_out, int out_size, void* d_ws, size_t ws_size,
                              hipStream_t stream) {
    const float* ent  = (const float*)d_in[0];
    const float* c0   = (const float*)d_in[1];
    const float* Wih  = (const float*)d_in[2];
    const float* Whh  = (const float*)d_in[3];
    const float* bih  = (const float*)d_in[4];
    const float* bhh  = (const float*)d_in[5];
    const int* esrc   = (const int*)d_in[6];
    const int* edst   = (const int*)d_in[7];
    const int* act    = (const int*)d_in[8];
    const int* susr   = (const int*)d_in[9];
    const int* stime  = (const int*)d_in[10];
    const int* crel   = (const int*)d_in[11];
    float* out = (float*)d_out;

    float* ws = (float*)d_ws;
    size_t o = 0;
    unsigned short* node16 = (unsigned short*)(ws + o); o += (size_t)NNODE * EMBD / 2;  // 51.2MB
    float* cxp   = ws + o; o += (size_t)NNODE * EMBD;                                    // 102.4MB (lazy)
    unsigned* msgu = (unsigned*)(ws + o); o += (size_t)NNODE * EMBD / 2;                 // 51.2MB
    float* u_emb = ws + o; o += (size_t)BB * 128;
    float* cnt   = ws + o; o += (size_t)NNODE;
    int*   stamp = (int*)(ws + o); o += (size_t)NNODE;
    short* w16   = (short*)(ws + o); o += (size_t)512 * 256 / 2;
    float* bsum  = ws + o; o += 512;
    short* c16   = (short*)(ws + o); o += (size_t)NPAD * 128 / 2;
    unsigned short* u16 = (unsigned short*)(ws + o); o += (size_t)BB * 128 / 2;
    // lse partials reuse msgu region (idle post-loop)
    float* pm = (float*)msgu;
    float* ps = pm + (size_t)BB * NT2P;

    init_kernel<<<2048, 256, 0, stream>>>((const float4*)ent, node16, (uint4*)msgu,
                                          cnt, stamp, out);
    convert_kernel<<<2048, 256, 0, stream>>>(Wih, Whh, bih, bhh, ent, w16, bsum, c16);

    for (int t = 0; t < TT; ++t) {
        const int* src_t = esrc + (size_t)t * EE;
        const int* dst_t = edst + (size_t)t * EE;
        const int* act_t = act + (size_t)t * AA;
        edge_snap<<<EE / 4 + BB / 2, 256, 0, stream>>>(src_t, dst_t, node16, msgu, cnt,
                                                       susr, stime, u_emb, u16, t);
        gates_mfma<<<AA / 16, 512, 0, stream>>>(node16, msgu, cnt, w16, bsum, act_t,
                                                cxp, c0, stamp, t);
        apply_kernel<<<NNODE / 8, 512, 0, stream>>>(node16, msgu, cnt);
    }

    snap31<<<BB / 2, 256, 0, stream>>>(node16, susr, stime, u_emb, u16);
    lse_mfma<<<dim3(NT2, 2), 512, 0, stream>>>((const short*)u16, c16, pm, ps);
    merge_final<<<BB / 4, 256, 0, stream>>>(pm, ps, u_emb, ent, crel, out);
}